// Round 4
// baseline (202.204 us; speedup 1.0000x reference)
//
#include <hip/hip_runtime.h>
#include <math.h>

typedef __bf16 bf16x8 __attribute__((ext_vector_type(8)));
typedef __bf16 bf16x4 __attribute__((ext_vector_type(4)));
typedef float f32x4 __attribute__((ext_vector_type(4)));

#define HDIM 128
#define PTS 32
#define NTHREADS 256
#define NBLK 512   // 2 blocks/CU x 256 CUs, persistent

#define EMV 0.001f
#define LFIX 0.05f
#define KFIX 100.0f
#define LAMBDA_L 0.5769230769230769f
#define MU_L 0.3846153846153846f

// swizzled bf16 index: 128-wide rows, 16B granules blk in [0,16)
__device__ __forceinline__ int swb(int r, int blk) {
    return (r << 7) + ((blk ^ (r & 7)) << 3);
}

__device__ __forceinline__ float fast_tanh(float x) {
    float xc = fminf(fmaxf(x, -10.f), 10.f);
    float e = __expf(2.f * xc);
    return (e - 1.f) / (e + 1.f);
}

__device__ __forceinline__ float wred(float v) {
#pragma unroll
    for (int off = 32; off > 0; off >>= 1) v += __shfl_down(v, off, 64);
    return v;
}

// full 128x128 W^T staging: Wl[n][j] = Wg[j][n], bf16 swizzled (one-time per block)
__device__ __forceinline__ void stage_wt_full(const float* __restrict__ Wg, __bf16* Wl, int tid) {
    const int n = tid & 127;
    const int j0base = (tid >> 7) * 64;
#pragma unroll
    for (int jj = 0; jj < 64; jj += 4) {
        int j0 = j0base + jj;
        float a = Wg[(j0 + 0) * HDIM + n];
        float b = Wg[(j0 + 1) * HDIM + n];
        float c = Wg[(j0 + 2) * HDIM + n];
        float d = Wg[(j0 + 3) * HDIM + n];
        bf16x4 pk = {(__bf16)a, (__bf16)b, (__bf16)c, (__bf16)d};
        *(bf16x4*)(Wl + swb(n, j0 >> 3) + (j0 & 7)) = pk;
    }
}

// Forward batched GEMM, A-fragments in registers (wf[r][ks]).
// out[p][n] = sum_j in[p][j] * W[j][n].  EPI0: buf0->tanh(+bias), bufs1..->acc*(1-h^2).
template <int NB>
__device__ __forceinline__ void gemm_fwd(const bf16x8 (&wf)[2][4],
                                         __bf16* const* inb, __bf16* const* outb,
                                         const float4 (&bias)[2], int tid) {
    const int lane = tid & 63, wid = tid >> 6, l15 = lane & 15, q = lane >> 4;
    f32x4 acc[NB][2][2];
#pragma unroll
    for (int b = 0; b < NB; ++b)
#pragma unroll
        for (int r = 0; r < 2; ++r)
#pragma unroll
            for (int c = 0; c < 2; ++c) acc[b][r][c] = (f32x4){0.f, 0.f, 0.f, 0.f};
    __syncthreads();  // inputs visible
#pragma unroll
    for (int ks = 0; ks < 4; ++ks) {
        const int kb = ks * 4 + q;
#pragma unroll
        for (int b = 0; b < NB; ++b) {
            bf16x8 bfr[2];
#pragma unroll
            for (int ct = 0; ct < 2; ++ct)
                bfr[ct] = *(const bf16x8*)(inb[b] + swb(ct * 16 + l15, kb));
#pragma unroll
            for (int r = 0; r < 2; ++r)
#pragma unroll
                for (int ct = 0; ct < 2; ++ct)
                    acc[b][r][ct] = __builtin_amdgcn_mfma_f32_16x16x32_bf16(
                        wf[r][ks], bfr[ct], acc[b][r][ct], 0, 0, 0);
        }
    }
    __syncthreads();  // all reads done before in-place writes
#pragma unroll
    for (int r = 0; r < 2; ++r) {
        const int n0 = (wid * 2 + r) * 16 + q * 4;
        float bias4[4] = {bias[r].x, bias[r].y, bias[r].z, bias[r].w};
#pragma unroll
        for (int ct = 0; ct < 2; ++ct) {
            const int p = ct * 16 + l15;
            const int widx = swb(p, n0 >> 3) + (n0 & 7);
            float fct[4];
            bf16x4 hv;
#pragma unroll
            for (int i = 0; i < 4; ++i) {
                float h = fast_tanh(acc[0][r][ct][i] + bias4[i]);
                hv[i] = (__bf16)h;
                fct[i] = 1.f - h * h;
            }
            *(bf16x4*)(outb[0] + widx) = hv;
#pragma unroll
            for (int b = 1; b < NB; ++b) {
                bf16x4 ov;
#pragma unroll
                for (int i = 0; i < 4; ++i) ov[i] = (__bf16)(acc[b][r][ct][i] * fct[i]);
                *(bf16x4*)(outb[b] + widx) = ov;
            }
        }
    }
}

// Backward (trace) GEMM: out[p][j] = sum_k in[p][k]*Wg[j][k]; A-fragments straight
// from global (rare tiles). Epilogue: *(1-href^2), in-place.
template <int NB>
__device__ __forceinline__ void gemm_bwd(const float* __restrict__ Wg,
                                         __bf16* const* inb, const __bf16* href, int tid) {
    const int lane = tid & 63, wid = tid >> 6, l15 = lane & 15, q = lane >> 4;
    f32x4 acc[NB][2][2];
#pragma unroll
    for (int b = 0; b < NB; ++b)
#pragma unroll
        for (int r = 0; r < 2; ++r)
#pragma unroll
            for (int c = 0; c < 2; ++c) acc[b][r][c] = (f32x4){0.f, 0.f, 0.f, 0.f};
    __syncthreads();
#pragma unroll
    for (int ks = 0; ks < 4; ++ks) {
        const int kb = ks * 4 + q;
        bf16x8 afr[2];
#pragma unroll
        for (int r = 0; r < 2; ++r) {
            int j = (wid * 2 + r) * 16 + l15;
            const float4* s = (const float4*)(Wg + j * HDIM + kb * 8);
            float4 v0 = s[0], v1 = s[1];
            afr[r] = (bf16x8){(__bf16)v0.x, (__bf16)v0.y, (__bf16)v0.z, (__bf16)v0.w,
                              (__bf16)v1.x, (__bf16)v1.y, (__bf16)v1.z, (__bf16)v1.w};
        }
#pragma unroll
        for (int b = 0; b < NB; ++b) {
            bf16x8 bfr[2];
#pragma unroll
            for (int ct = 0; ct < 2; ++ct)
                bfr[ct] = *(const bf16x8*)(inb[b] + swb(ct * 16 + l15, kb));
#pragma unroll
            for (int r = 0; r < 2; ++r)
#pragma unroll
                for (int ct = 0; ct < 2; ++ct)
                    acc[b][r][ct] = __builtin_amdgcn_mfma_f32_16x16x32_bf16(
                        afr[r], bfr[ct], acc[b][r][ct], 0, 0, 0);
        }
    }
    __syncthreads();
#pragma unroll
    for (int r = 0; r < 2; ++r) {
        const int n0 = (wid * 2 + r) * 16 + q * 4;
#pragma unroll
        for (int ct = 0; ct < 2; ++ct) {
            const int p = ct * 16 + l15;
            const int widx = swb(p, n0 >> 3) + (n0 & 7);
            bf16x4 hv = *(const bf16x4*)(href + widx);
#pragma unroll
            for (int b = 0; b < NB; ++b) {
                bf16x4 ov;
#pragma unroll
                for (int i = 0; i < 4; ++i) {
                    float h = (float)hv[i];
                    ov[i] = (__bf16)(acc[b][r][ct][i] * (1.f - h * h));
                }
                *(bf16x4*)(inb[b] + widx) = ov;
            }
        }
    }
}

__device__ __forceinline__ void dnorms32(const __bf16* a, const __bf16* b, const __bf16* c2,
                                         float* npart, int tid) {
    int p = tid & 31, cc = tid >> 5;
    float s0 = 0.f, s1 = 0.f, s2 = 0.f;
#pragma unroll
    for (int blk = cc * 2; blk < cc * 2 + 2; ++blk) {
        bf16x8 v0 = *(const bf16x8*)(a + swb(p, blk));
        bf16x8 v1 = *(const bf16x8*)(b + swb(p, blk));
        bf16x8 v2 = *(const bf16x8*)(c2 + swb(p, blk));
#pragma unroll
        for (int e = 0; e < 8; ++e) {
            float f0 = (float)v0[e], f1 = (float)v1[e], f2 = (float)v2[e];
            s0 += f0 * f0; s1 += f1 * f1; s2 += f2 * f2;
        }
    }
    npart[(0 + cc) * PTS + p] = s0;
    npart[(8 + cc) * PTS + p] = s1;
    npart[(16 + cc) * PTS + p] = s2;
}

__device__ __forceinline__ float sum8(const float* npart, int buf, int p) {
    float d = 0.f;
#pragma unroll
    for (int i = 0; i < 8; ++i) d += npart[(buf * 8 + i) * PTS + p];
    return d;
}
__device__ __forceinline__ float sum24(const float* npart, int p) {
    float d = 0.f;
#pragma unroll
    for (int i = 0; i < 24; ++i) d += npart[i * PTS + p];
    return d;
}

__global__ void __launch_bounds__(NTHREADS, 2) pinn_persist(
    const float* __restrict__ xPhys, const float* __restrict__ coord,
    const float* __restrict__ W1, const float* __restrict__ b1,
    const float* __restrict__ W2, const float* __restrict__ b2,
    const float* __restrict__ W3, const float* __restrict__ b3,
    const float* __restrict__ W4, const float* __restrict__ b4,
    const float* __restrict__ fc, const float* __restrict__ Fv,
    const int* __restrict__ nfixp,
    float* __restrict__ out, float* __restrict__ acc,
    int nmain, int ntot, int Ntot) {
    // act arena: 6 buffers of 32x128 bf16 (h1,h2,h3,t0,t1,t2); first 32 KB doubles
    // as one-time W staging scratch.
    __shared__ __align__(16) __bf16 arena[6 * PTS * HDIM];   // 48 KB
    __shared__ __align__(16) __bf16 W4p[16 * HDIM];          // 4 KB
    __shared__ __align__(16) float W4ts[3 * HDIM];
    __shared__ __align__(16) float xss[PTS * 4];
    __shared__ float xp3s[PTS], nh1s[PTS], nh2s[PTS], nh3s[PTS], nxs[PTS];
    __shared__ float npart[24 * PTS];
    __shared__ float gls[PTS * 12];
    __shared__ float uls[PTS * 4];

    __bf16* h1s = arena + 0 * PTS * HDIM;
    __bf16* h2s = arena + 1 * PTS * HDIM;
    __bf16* h3s = arena + 2 * PTS * HDIM;
    __bf16* t0s = arena + 3 * PTS * HDIM;
    __bf16* t1s = arena + 4 * PTS * HDIM;
    __bf16* t2s = arena + 5 * PTS * HDIM;

    const int tid = threadIdx.x;
    const int lane = tid & 63, wid = tid >> 6, l15 = lane & 15, q = lane >> 4;
    const int nfixv = nfixp[0];

    float* energy_c_out = out + 1;
    float* u_out = out + 1 + Ntot;

    // ---------- one-time preload: weights into registers ----------
    bf16x8 w2f[2][4], w3f[2][4], w4f[4];
    float4 bias2[2], bias3[2];
#pragma unroll
    for (int r = 0; r < 2; ++r) {
        int n0 = (wid * 2 + r) * 16 + q * 4;
        bias2[r] = *(const float4*)(b2 + n0);
        bias3[r] = *(const float4*)(b3 + n0);
    }
    {  // W4p (padded W4^T bf16) + W4ts (fp32)
        int o = tid >> 4, blk = tid & 15, j0 = blk * 8;
        bf16x8 pk;
#pragma unroll
        for (int e = 0; e < 8; ++e) {
            float v = (o < 3) ? W4[(j0 + e) * 3 + o] : 0.f;
            pk[e] = (__bf16)v;
            if (o < 3) W4ts[o * HDIM + j0 + e] = v;
        }
        *(bf16x8*)(W4p + swb(o, blk)) = pk;
    }
    stage_wt_full(W2, arena, tid);
    __syncthreads();
#pragma unroll
    for (int r = 0; r < 2; ++r)
#pragma unroll
        for (int ks = 0; ks < 4; ++ks)
            w2f[r][ks] = *(const bf16x8*)(arena + swb((wid * 2 + r) * 16 + l15, ks * 4 + q));
#pragma unroll
    for (int ks = 0; ks < 4; ++ks)
        w4f[ks] = *(const bf16x8*)(W4p + swb(l15, ks * 4 + q));
    __syncthreads();
    stage_wt_full(W3, arena, tid);
    __syncthreads();
#pragma unroll
    for (int r = 0; r < 2; ++r)
#pragma unroll
        for (int ks = 0; ks < 4; ++ks)
            w3f[r][ks] = *(const bf16x8*)(arena + swb((wid * 2 + r) * 16 + l15, ks * 4 + q));

    // ---------- persistent tile loop ----------
    for (int t = blockIdx.x; t < ntot; t += NBLK) {
        if (t < nmain) {
            const int base = t * PTS;
            const bool fullfix = (base + PTS) <= nfixv;
            const bool fullrr = base >= nfixv;
            const bool do_trace = fullfix ? ((t & 7) == 0) : (fullrr ? ((t & 15) == 8) : true);

            if (tid < 3 * PTS) xss[(tid / 3) * 4 + (tid % 3)] = coord[base * 3 + tid];
            if (tid >= 96 && tid < 96 + PTS) {
                int p = tid - 96;
                float xp = xPhys[base + p];
                xp3s[p] = xp * xp * xp;
            }
            __syncthreads();

            // layer 1 + tangent seeds
#pragma unroll
            for (int it = 0; it < 2; ++it) {
                int f = tid + it * NTHREADS;
                int p = f >> 4, blk = f & 15, j0 = blk * 8;
                float x0 = xss[p * 4], x1 = xss[p * 4 + 1], x2 = xss[p * 4 + 2];
                bf16x8 hv, t0v, t1v, t2v;
#pragma unroll
                for (int jj = 0; jj < 8; ++jj) {
                    int j = j0 + jj;
                    float w0 = W1[j], w1 = W1[HDIM + j], w2 = W1[2 * HDIM + j];
                    float z = b1[j] + x0 * w0 + x1 * w1 + x2 * w2;
                    float h = fast_tanh(z);
                    float fct = 1.f - h * h;
                    hv[jj] = (__bf16)h;
                    t0v[jj] = (__bf16)(fct * w0);
                    t1v[jj] = (__bf16)(fct * w1);
                    t2v[jj] = (__bf16)(fct * w2);
                }
                int wi = swb(p, blk);
                *(bf16x8*)(h1s + wi) = hv;
                *(bf16x8*)(t0s + wi) = t0v;
                *(bf16x8*)(t1s + wi) = t1v;
                *(bf16x8*)(t2s + wi) = t2v;
            }
            {
                __bf16* ib[4] = {h1s, t0s, t1s, t2s};
                __bf16* ob[4] = {h2s, t0s, t1s, t2s};
                gemm_fwd<4>(w2f, ib, ob, bias2, tid);
            }
            {
                __bf16* ib[4] = {h2s, t0s, t1s, t2s};
                __bf16* ob[4] = {h3s, t0s, t1s, t2s};
                gemm_fwd<4>(w3f, ib, ob, bias3, tid);
            }
            __syncthreads();  // h3/t writes visible for head

            if (wid < 2) {  // head: u + Jacobian columns
                __bf16* bl[4] = {h3s, t0s, t1s, t2s};
                f32x4 ha[4];
#pragma unroll
                for (int b = 0; b < 4; ++b) ha[b] = (f32x4){0.f, 0.f, 0.f, 0.f};
#pragma unroll
                for (int ks = 0; ks < 4; ++ks) {
                    int kb = ks * 4 + q;
#pragma unroll
                    for (int b = 0; b < 4; ++b) {
                        bf16x8 bf_ = *(const bf16x8*)(bl[b] + swb(wid * 16 + l15, kb));
                        ha[b] = __builtin_amdgcn_mfma_f32_16x16x32_bf16(w4f[ks], bf_, ha[b], 0, 0, 0);
                    }
                }
                if (q == 0) {
                    int p = wid * 16 + l15;
#pragma unroll
                    for (int o = 0; o < 3; ++o) {
                        float uv = ha[0][o] + b4[o];
                        uls[p * 4 + o] = uv;
                        u_out[(base + p) * 3 + o] = uv;
                    }
#pragma unroll
                    for (int b = 1; b < 4; ++b)
#pragma unroll
                        for (int o = 0; o < 3; ++o) gls[p * 12 + (b - 1) * 3 + o] = ha[b][o];
                }
            }
            __syncthreads();

            // energy + E_fix (wave 0)
            if (tid < 64) {
                float ef = 0.f, er = 0.f;
                if (tid < PTS) {
                    int p = tid;
                    float x0 = xss[p * 4];
                    float sc = fminf(fmaxf(x0 * (1.f / LFIX), 0.f), 1.f);
                    if ((base + p) < nfixv && sc == 0.f) {
                        float u0 = uls[p * 4], u1 = uls[p * 4 + 1], u2 = uls[p * 4 + 2];
                        ef = xp3s[p] * 0.5f * KFIX * (u0 * u0 + u1 * u1 + u2 * u2);
                    }
                    float g00 = gls[p * 12 + 0], g01 = gls[p * 12 + 1], g02 = gls[p * 12 + 2];
                    float g10 = gls[p * 12 + 3], g11 = gls[p * 12 + 4], g12 = gls[p * 12 + 5];
                    float g20 = gls[p * 12 + 6], g21 = gls[p * 12 + 7], g22 = gls[p * 12 + 8];
                    float e11 = g11, e22 = g00, e33 = g22;
                    float e12 = 0.5f * (g01 + g10);
                    float e13 = 0.5f * (g21 + g12);
                    float e23 = 0.5f * (g20 + g02);
                    float tr = e11 + e22 + e33;
                    float en = 0.5f * LAMBDA_L * tr * tr +
                               MU_L * (e11 * e11 + e22 * e22 + e33 * e33 +
                                       2.f * (e12 * e12 + e13 * e13 + e23 * e23));
                    float exp3 = en * xp3s[p];
                    energy_c_out[base + p] = 2.f * exp3;
                    er = exp3;
                }
                ef = wred(ef);
                er = wred(er);
                if (tid == 0) {
                    atomicAdd(acc + 1, ef);
                    atomicAdd(acc + 0, er);
                }
            }

            if (do_trace) {
                // delta3 seeds into t0..t2 (tangents no longer needed)
#pragma unroll
                for (int it = 0; it < 2; ++it) {
                    int f = tid + it * NTHREADS;
                    int p = f >> 4, blk = f & 15, j0 = blk * 8;
                    bf16x8 h3v = *(const bf16x8*)(h3s + swb(p, blk));
                    bf16x8 d0, d1, d2;
#pragma unroll
                    for (int e = 0; e < 8; ++e) {
                        float h = (float)h3v[e];
                        float fct = 1.f - h * h;
                        d0[e] = (__bf16)(fct * W4ts[j0 + e]);
                        d1[e] = (__bf16)(fct * W4ts[HDIM + j0 + e]);
                        d2[e] = (__bf16)(fct * W4ts[2 * HDIM + j0 + e]);
                    }
                    int wi = swb(p, blk);
                    *(bf16x8*)(t0s + wi) = d0;
                    *(bf16x8*)(t1s + wi) = d1;
                    *(bf16x8*)(t2s + wi) = d2;
                }
                dnorms32(h1s, h2s, h3s, npart, tid);
                __syncthreads();
                if (tid < PTS) {
                    int p = tid;
                    nh1s[p] = sum8(npart, 0, p);
                    nh2s[p] = sum8(npart, 1, p);
                    nh3s[p] = sum8(npart, 2, p);
                    float x0 = xss[p * 4], x1 = xss[p * 4 + 1], x2 = xss[p * 4 + 2];
                    nxs[p] = x0 * x0 + x1 * x1 + x2 * x2;
                }
                __syncthreads();
                dnorms32(t0s, t1s, t2s, npart, tid);   // ||d3||^2
                __syncthreads();
                float s_acc = 0.f;
                if (tid < PTS) s_acc = sum24(npart, tid) * (1.f + nh2s[tid]);
                {
                    __bf16* ib[3] = {t0s, t1s, t2s};
                    gemm_bwd<3>(W3, ib, h2s, tid);     // delta2
                }
                __syncthreads();
                dnorms32(t0s, t1s, t2s, npart, tid);   // ||d2||^2
                __syncthreads();
                if (tid < PTS) s_acc += sum24(npart, tid) * (1.f + nh1s[tid]);
                {
                    __bf16* ib[3] = {t0s, t1s, t2s};
                    gemm_bwd<3>(W2, ib, h1s, tid);     // delta1
                }
                __syncthreads();
                dnorms32(t0s, t1s, t2s, npart, tid);   // ||d1||^2
                __syncthreads();
                if (tid < 64) {
                    float su = 0.f, sr = 0.f, cu = 0.f, cr = 0.f;
                    if (tid < PTS) {
                        int p = tid;
                        float s = s_acc + sum24(npart, p) * (1.f + nxs[p]) + 3.f * (nh3s[p] + 1.f);
                        bool uu = (base + p) < nfixv;
                        su = uu ? s : 0.f;
                        sr = uu ? 0.f : s;
                        cu = uu ? 1.f : 0.f;
                        cr = uu ? 0.f : 1.f;
                    }
                    su = wred(su); sr = wred(sr); cu = wred(cu); cr = wred(cr);
                    if (tid == 0) {
                        atomicAdd(acc + 3, su);
                        atomicAdd(acc + 4, sr);
                        atomicAdd(acc + 5, cu);
                        atomicAdd(acc + 6, cr);
                    }
                }
            }
            __syncthreads();  // protect xss/acts for next tile
        } else {
            // ---------------- force tile ----------------
            const int fbase = (t - nmain) * PTS;
            if (tid < 3 * PTS) xss[(tid / 3) * 4 + (tid % 3)] = fc[fbase * 3 + tid];
            __syncthreads();
#pragma unroll
            for (int it = 0; it < 2; ++it) {
                int f = tid + it * NTHREADS;
                int p = f >> 4, blk = f & 15, j0 = blk * 8;
                float x0 = xss[p * 4], x1 = xss[p * 4 + 1], x2 = xss[p * 4 + 2];
                bf16x8 hv;
#pragma unroll
                for (int jj = 0; jj < 8; ++jj) {
                    int j = j0 + jj;
                    float z = b1[j] + x0 * W1[j] + x1 * W1[HDIM + j] + x2 * W1[2 * HDIM + j];
                    hv[jj] = (__bf16)fast_tanh(z);
                }
                *(bf16x8*)(h1s + swb(p, blk)) = hv;
            }
            {
                __bf16* ib[1] = {h1s};
                gemm_fwd<1>(w2f, ib, ib, bias2, tid);
            }
            {
                __bf16* ib[1] = {h1s};
                gemm_fwd<1>(w3f, ib, ib, bias3, tid);
            }
            __syncthreads();
            if (wid < 2) {
                f32x4 ha = (f32x4){0.f, 0.f, 0.f, 0.f};
#pragma unroll
                for (int ks = 0; ks < 4; ++ks) {
                    bf16x8 bf_ = *(const bf16x8*)(h1s + swb(wid * 16 + l15, ks * 4 + q));
                    ha = __builtin_amdgcn_mfma_f32_16x16x32_bf16(w4f[ks], bf_, ha, 0, 0, 0);
                }
                if (q == 0) {
                    int p = wid * 16 + l15;
#pragma unroll
                    for (int o = 0; o < 3; ++o) uls[p * 4 + o] = ha[o] + b4[o];
                }
            }
            __syncthreads();
            if (tid < 64) {
                float fsum = 0.f;
                if (tid < PTS)
                    fsum = uls[tid * 4] * Fv[0] + uls[tid * 4 + 1] * Fv[1] + uls[tid * 4 + 2] * Fv[2];
                fsum = wred(fsum);
                if (tid == 0) atomicAdd(acc + 2, fsum);
            }
            __syncthreads();
        }
    }

    // ---------- last-block finalization ----------
    if (tid == 0) {
        __threadfence();
        unsigned old = atomicAdd((unsigned*)(acc + 7), 1u);
        if (old == (unsigned)(NBLK - 1)) {
            __threadfence();
            float es = atomicAdd(acc + 0, 0.f);
            float ef = atomicAdd(acc + 1, 0.f);
            float fl = atomicAdd(acc + 2, 0.f);
            float su = atomicAdd(acc + 3, 0.f);
            float sr = atomicAdd(acc + 4, 0.f);
            float cu = atomicAdd(acc + 5, 0.f);
            float cr = atomicAdd(acc + 6, 0.f);
            float nfixf = (float)nfixv;
            float tu = su / fmaxf(cu, 1.f) * nfixf;
            float tr = sr / fmaxf(cr, 1.f) * ((float)Ntot - nfixf);
            float energy_ans = EMV * (es / (float)Ntot);
            float E_fix = ef * EMV / (float)Ntot;
            float lam = tr / (tu + 1e-12f);
            lam = fminf(fmaxf(lam, 0.001f), 1000.f);
            out[0] = energy_ans - fl + lam * E_fix;
        }
    }
}

extern "C" void kernel_launch(void* const* d_in, const int* in_sizes, int n_in,
                              void* d_out, int out_size, void* d_ws, size_t ws_size,
                              hipStream_t stream) {
    const float* xPhys = (const float*)d_in[0];
    const float* coord = (const float*)d_in[1];
    const float* W1 = (const float*)d_in[2];
    const float* b1 = (const float*)d_in[3];
    const float* W2 = (const float*)d_in[4];
    const float* b2 = (const float*)d_in[5];
    const float* W3 = (const float*)d_in[6];
    const float* b3 = (const float*)d_in[7];
    const float* W4 = (const float*)d_in[8];
    const float* b4 = (const float*)d_in[9];
    const float* fc = (const float*)d_in[10];
    const float* Fv = (const float*)d_in[11];
    const int* nfix = (const int*)d_in[12];

    const int N = in_sizes[0];        // 65536
    const int NF = in_sizes[10] / 3;  // 4096
    float* out = (float*)d_out;
    float* acc = (float*)d_ws;  // [energy, efix, force, su, sr, cnt_u, cnt_r, ticket]

    const int nmain = N / PTS;
    const int ntot = nmain + NF / PTS;
    hipMemsetAsync(acc, 0, 8 * sizeof(float), stream);
    pinn_persist<<<dim3(NBLK), dim3(NTHREADS), 0, stream>>>(
        xPhys, coord, W1, b1, W2, b2, W3, b3, W4, b4, fc, Fv, nfix,
        out, acc, nmain, ntot, N);
}

// Round 5
// 195.295 us; speedup vs baseline: 1.0354x; 1.0354x over previous
//
#include <hip/hip_runtime.h>
#include <math.h>

typedef __bf16 bf16x8 __attribute__((ext_vector_type(8)));
typedef __bf16 bf16x4 __attribute__((ext_vector_type(4)));
typedef float f32x4 __attribute__((ext_vector_type(4)));

#define HDIM 128
#define PTS 64          // points per workgroup (4 col-tiles of 16)
#define NTHREADS 512    // 8 waves

#define EMV 0.001f
#define LFIX 0.05f
#define KFIX 100.0f
#define LAMBDA_L 0.5769230769230769f
#define MU_L 0.3846153846153846f

// swizzled bf16 index: 128-wide rows, 16B granules blk in [0,16)
__device__ __forceinline__ int swb(int r, int blk) {
    return (r << 7) + ((blk ^ (r & 7)) << 3);
}
// swizzled bf16 index: 64-wide rows (weight K-chunk), granules blk in [0,8)
__device__ __forceinline__ int swb64(int r, int blk) {
    return (r << 6) + ((blk ^ (r & 7)) << 3);
}

__device__ __forceinline__ float fast_tanh(float x) {
    float xc = fminf(fmaxf(x, -10.f), 10.f);
    float e = __expf(2.f * xc);
    return (e - 1.f) / (e + 1.f);
}

__device__ __forceinline__ float wred(float v) {
#pragma unroll
    for (int off = 32; off > 0; off >>= 1) v += __shfl_down(v, off, 64);
    return v;
}

// Forward batched GEMM over 64 points, chunk-staged W^T in LDS.
// out[p][n] = sum_j in[p][j] * W[j][n].
// Wave layout: rt0=(wid>>1)*2 row-tiles, ct0=(wid&1)*2 col-tiles.
// buf0 -> tanh(acc+bias); bufs 1.. -> acc*(1-h^2) with local fp32 h. In-place safe.
template <int NB>
__device__ __forceinline__ void gemm_fwd(const float* __restrict__ Wg, __bf16* Wst,
                                         __bf16* const* inb, __bf16* const* outb,
                                         const float* __restrict__ biasg, int tid) {
    const int lane = tid & 63, wid = tid >> 6, l15 = lane & 15, q = lane >> 4;
    const int rt0 = (wid >> 1) * 2, ct0 = (wid & 1) * 2;
    f32x4 acc[NB][2][2];
#pragma unroll
    for (int b = 0; b < NB; ++b)
#pragma unroll
        for (int r = 0; r < 2; ++r)
#pragma unroll
            for (int c = 0; c < 2; ++c) acc[b][r][c] = (f32x4){0.f, 0.f, 0.f, 0.f};

#pragma unroll
    for (int c = 0; c < 2; ++c) {
        __syncthreads();  // previous Wst users / input writes done
        {   // stage: Wst[n][jl] = Wg[(c*64+jl)*128 + n]
            const int n = tid & 127, jb = (tid >> 7) * 16;
#pragma unroll
            for (int jj = 0; jj < 16; jj += 4) {
                int jl = jb + jj;
                float a = Wg[(c * 64 + jl + 0) * HDIM + n];
                float b = Wg[(c * 64 + jl + 1) * HDIM + n];
                float d = Wg[(c * 64 + jl + 2) * HDIM + n];
                float e = Wg[(c * 64 + jl + 3) * HDIM + n];
                bf16x4 pk = {(__bf16)a, (__bf16)b, (__bf16)d, (__bf16)e};
                *(bf16x4*)(Wst + swb64(n, jl >> 3) + (jl & 7)) = pk;
            }
        }
        __syncthreads();
#pragma unroll
        for (int ks = 0; ks < 2; ++ks) {
            bf16x8 afr[2];
#pragma unroll
            for (int r = 0; r < 2; ++r)
                afr[r] = *(const bf16x8*)(Wst + swb64((rt0 + r) * 16 + l15, ks * 4 + q));
#pragma unroll
            for (int b = 0; b < NB; ++b) {
                bf16x8 bfr[2];
#pragma unroll
                for (int ct = 0; ct < 2; ++ct)
                    bfr[ct] = *(const bf16x8*)(inb[b] + swb((ct0 + ct) * 16 + l15, c * 8 + ks * 4 + q));
#pragma unroll
                for (int r = 0; r < 2; ++r)
#pragma unroll
                    for (int ct = 0; ct < 2; ++ct)
                        acc[b][r][ct] = __builtin_amdgcn_mfma_f32_16x16x32_bf16(
                            afr[r], bfr[ct], acc[b][r][ct], 0, 0, 0);
            }
        }
    }
    __syncthreads();  // all B reads done before in-place writes
#pragma unroll
    for (int r = 0; r < 2; ++r) {
        const int n0 = (rt0 + r) * 16 + q * 4;
        float4 bv = *(const float4*)(biasg + n0);
        float bias4[4] = {bv.x, bv.y, bv.z, bv.w};
#pragma unroll
        for (int ct = 0; ct < 2; ++ct) {
            const int p = (ct0 + ct) * 16 + l15;
            const int widx = swb(p, n0 >> 3) + (n0 & 7);
            float fct[4];
            bf16x4 hv;
#pragma unroll
            for (int i = 0; i < 4; ++i) {
                float h = fast_tanh(acc[0][r][ct][i] + bias4[i]);
                hv[i] = (__bf16)h;
                fct[i] = 1.f - h * h;
            }
            *(bf16x4*)(outb[0] + widx) = hv;
#pragma unroll
            for (int b = 1; b < NB; ++b) {
                bf16x4 ov;
#pragma unroll
                for (int i = 0; i < 4; ++i) ov[i] = (__bf16)(acc[b][r][ct][i] * fct[i]);
                *(bf16x4*)(outb[b] + widx) = ov;
            }
        }
    }
}

// Backward (trace) GEMM: out[p][j] = sum_k in[p][k]*Wg[j][k]; A-frags from global
// (rare tiles, L2-hot). Epilogue *(1-href^2), in-place.
template <int NB>
__device__ __forceinline__ void gemm_bwd(const float* __restrict__ Wg,
                                         __bf16* const* inb, const __bf16* href, int tid) {
    const int lane = tid & 63, wid = tid >> 6, l15 = lane & 15, q = lane >> 4;
    const int rt0 = (wid >> 1) * 2, ct0 = (wid & 1) * 2;
    f32x4 acc[NB][2][2];
#pragma unroll
    for (int b = 0; b < NB; ++b)
#pragma unroll
        for (int r = 0; r < 2; ++r)
#pragma unroll
            for (int c = 0; c < 2; ++c) acc[b][r][c] = (f32x4){0.f, 0.f, 0.f, 0.f};
    __syncthreads();  // inputs visible
#pragma unroll
    for (int ks = 0; ks < 4; ++ks) {
        const int kb = ks * 4 + q;
        bf16x8 afr[2];
#pragma unroll
        for (int r = 0; r < 2; ++r) {
            int j = (rt0 + r) * 16 + l15;
            const float4* s = (const float4*)(Wg + j * HDIM + kb * 8);
            float4 v0 = s[0], v1 = s[1];
            afr[r] = (bf16x8){(__bf16)v0.x, (__bf16)v0.y, (__bf16)v0.z, (__bf16)v0.w,
                              (__bf16)v1.x, (__bf16)v1.y, (__bf16)v1.z, (__bf16)v1.w};
        }
#pragma unroll
        for (int b = 0; b < NB; ++b) {
            bf16x8 bfr[2];
#pragma unroll
            for (int ct = 0; ct < 2; ++ct)
                bfr[ct] = *(const bf16x8*)(inb[b] + swb((ct0 + ct) * 16 + l15, kb));
#pragma unroll
            for (int r = 0; r < 2; ++r)
#pragma unroll
                for (int ct = 0; ct < 2; ++ct)
                    acc[b][r][ct] = __builtin_amdgcn_mfma_f32_16x16x32_bf16(
                        afr[r], bfr[ct], acc[b][r][ct], 0, 0, 0);
        }
    }
    __syncthreads();
#pragma unroll
    for (int r = 0; r < 2; ++r) {
        const int n0 = (rt0 + r) * 16 + q * 4;
#pragma unroll
        for (int ct = 0; ct < 2; ++ct) {
            const int p = (ct0 + ct) * 16 + l15;
            const int widx = swb(p, n0 >> 3) + (n0 & 7);
            bf16x4 hv = *(const bf16x4*)(href + widx);
#pragma unroll
            for (int b = 0; b < NB; ++b) {
                bf16x4 ov;
#pragma unroll
                for (int i = 0; i < 4; ++i) {
                    float h = (float)hv[i];
                    ov[i] = (__bf16)(acc[b][r][ct][i] * (1.f - h * h));
                }
                *(bf16x4*)(inb[b] + widx) = ov;
            }
        }
    }
}

// partial sum-of-squares of 3 buffers: npart[(buf*8+cc)*64+p], cc in [0,8), 2 granules each
__device__ __forceinline__ void dnorms64(const __bf16* a, const __bf16* b, const __bf16* c2,
                                         float* npart, int tid) {
    int p = tid & 63, cc = tid >> 6;
    float s0 = 0.f, s1 = 0.f, s2 = 0.f;
#pragma unroll
    for (int blk = cc * 2; blk < cc * 2 + 2; ++blk) {
        bf16x8 v0 = *(const bf16x8*)(a + swb(p, blk));
        bf16x8 v1 = *(const bf16x8*)(b + swb(p, blk));
        bf16x8 v2 = *(const bf16x8*)(c2 + swb(p, blk));
#pragma unroll
        for (int e = 0; e < 8; ++e) {
            float f0 = (float)v0[e], f1 = (float)v1[e], f2 = (float)v2[e];
            s0 += f0 * f0; s1 += f1 * f1; s2 += f2 * f2;
        }
    }
    npart[(0 + cc) * PTS + p] = s0;
    npart[(8 + cc) * PTS + p] = s1;
    npart[(16 + cc) * PTS + p] = s2;
}

__device__ __forceinline__ float sum8(const float* npart, int buf, int p) {
    float d = 0.f;
#pragma unroll
    for (int i = 0; i < 8; ++i) d += npart[(buf * 8 + i) * PTS + p];
    return d;
}
__device__ __forceinline__ float sum24(const float* npart, int p) {
    float d = 0.f;
#pragma unroll
    for (int i = 0; i < 24; ++i) d += npart[i * PTS + p];
    return d;
}

__global__ void __launch_bounds__(NTHREADS, 2) pinn_all(
    const float* __restrict__ xPhys, const float* __restrict__ coord,
    const float* __restrict__ W1, const float* __restrict__ b1,
    const float* __restrict__ W2, const float* __restrict__ b2,
    const float* __restrict__ W3, const float* __restrict__ b3,
    const float* __restrict__ W4, const float* __restrict__ b4,
    const float* __restrict__ fc, const float* __restrict__ Fv,
    const int* __restrict__ nfixp,
    float* __restrict__ energy_c_out, float* __restrict__ u_out,
    float* __restrict__ acc, int nmain) {
    __shared__ __align__(16) __bf16 h1s[PTS * HDIM], h2s[PTS * HDIM], h3s[PTS * HDIM];
    __shared__ __align__(16) __bf16 t0s[PTS * HDIM], t1s[PTS * HDIM], t2s[PTS * HDIM];
    __shared__ __align__(16) __bf16 Wstage[64 * HDIM];   // 16 KB chunk
    __shared__ __align__(16) __bf16 W4p[16 * HDIM];      // 4 KB padded W4^T
    __shared__ __align__(16) float W4ts[3 * HDIM];
    __shared__ __align__(16) float xss[PTS * 4];
    __shared__ float xp3s[PTS], nh1s[PTS], nh2s[PTS], nh3s[PTS], nxs[PTS];
    __shared__ float npart[24 * PTS];
    __shared__ float gls[PTS * 12];
    __shared__ float uls[PTS * 4];

    const int tid = threadIdx.x;
    const int lane = tid & 63, wid = tid >> 6, l15 = lane & 15, q = lane >> 4;
    const int bi = blockIdx.x;

    if (bi < nmain) {
        // ================= main path: 64 coord points =================
        const int base = bi * PTS;
        const int nfixv = nfixp[0];
        const bool fullfix = (base + PTS) <= nfixv;
        const bool fullrr = base >= nfixv;
        const bool do_trace = fullfix ? ((bi & 3) == 0) : (fullrr ? ((bi & 15) == 4) : true);

        if (tid < 3 * PTS) xss[(tid / 3) * 4 + (tid % 3)] = coord[base * 3 + tid];
        if (tid >= 192 && tid < 192 + PTS) {
            int p = tid - 192;
            float xp = xPhys[base + p];
            xp3s[p] = xp * xp * xp;
        }
        if (tid >= 256 && tid < 512) {  // W4p + W4ts
            int e = tid - 256;
            int o = e >> 4, blk = e & 15, j0 = blk * 8;
            bf16x8 pk;
#pragma unroll
            for (int i = 0; i < 8; ++i) {
                float v = (o < 3) ? W4[(j0 + i) * 3 + o] : 0.f;
                pk[i] = (__bf16)v;
                if (o < 3) W4ts[o * HDIM + j0 + i] = v;
            }
            *(bf16x8*)(W4p + swb(o, blk)) = pk;
        }
        __syncthreads();

        // layer 1 + tangent seeds
#pragma unroll
        for (int it = 0; it < 2; ++it) {
            int f = tid + it * NTHREADS;
            int p = f >> 4, blk = f & 15, j0 = blk * 8;
            float x0 = xss[p * 4], x1 = xss[p * 4 + 1], x2 = xss[p * 4 + 2];
            bf16x8 hv, t0v, t1v, t2v;
#pragma unroll
            for (int jj = 0; jj < 8; ++jj) {
                int j = j0 + jj;
                float w0 = W1[j], w1 = W1[HDIM + j], w2 = W1[2 * HDIM + j];
                float z = b1[j] + x0 * w0 + x1 * w1 + x2 * w2;
                float h = fast_tanh(z);
                float fct = 1.f - h * h;
                hv[jj] = (__bf16)h;
                t0v[jj] = (__bf16)(fct * w0);
                t1v[jj] = (__bf16)(fct * w1);
                t2v[jj] = (__bf16)(fct * w2);
            }
            int wi = swb(p, blk);
            *(bf16x8*)(h1s + wi) = hv;
            *(bf16x8*)(t0s + wi) = t0v;
            *(bf16x8*)(t1s + wi) = t1v;
            *(bf16x8*)(t2s + wi) = t2v;
        }
        {  // layer 2 (fwd + 3 tangents)
            __bf16* ib[4] = {h1s, t0s, t1s, t2s};
            __bf16* ob[4] = {h2s, t0s, t1s, t2s};
            gemm_fwd<4>(W2, Wstage, ib, ob, b2, tid);
        }
        {  // layer 3
            __bf16* ib[4] = {h2s, t0s, t1s, t2s};
            __bf16* ob[4] = {h3s, t0s, t1s, t2s};
            gemm_fwd<4>(W3, Wstage, ib, ob, b3, tid);
        }
        __syncthreads();

        // head: u + Jacobian columns (waves 0..3, p-tile = wid)
        if (wid < 4) {
            __bf16* bl[4] = {h3s, t0s, t1s, t2s};
            f32x4 ha[4];
#pragma unroll
            for (int b = 0; b < 4; ++b) ha[b] = (f32x4){0.f, 0.f, 0.f, 0.f};
#pragma unroll
            for (int ks = 0; ks < 4; ++ks) {
                int kb = ks * 4 + q;
                bf16x8 af = *(const bf16x8*)(W4p + swb(l15, kb));
#pragma unroll
                for (int b = 0; b < 4; ++b) {
                    bf16x8 bf_ = *(const bf16x8*)(bl[b] + swb(wid * 16 + l15, kb));
                    ha[b] = __builtin_amdgcn_mfma_f32_16x16x32_bf16(af, bf_, ha[b], 0, 0, 0);
                }
            }
            if (q == 0) {
                int p = wid * 16 + l15;
#pragma unroll
                for (int o = 0; o < 3; ++o) {
                    float uv = ha[0][o] + b4[o];
                    uls[p * 4 + o] = uv;
                    u_out[(base + p) * 3 + o] = uv;
                }
#pragma unroll
                for (int b = 1; b < 4; ++b)
#pragma unroll
                    for (int o = 0; o < 3; ++o) gls[p * 12 + (b - 1) * 3 + o] = ha[b][o];
            }
        }
        __syncthreads();

        // energy + E_fix (wave 0, all 64 lanes busy)
        if (tid < 64) {
            int p = tid;
            float x0 = xss[p * 4];
            float sc = fminf(fmaxf(x0 * (1.f / LFIX), 0.f), 1.f);
            float ef = 0.f;
            if ((base + p) < nfixv && sc == 0.f) {
                float u0 = uls[p * 4], u1 = uls[p * 4 + 1], u2 = uls[p * 4 + 2];
                ef = xp3s[p] * 0.5f * KFIX * (u0 * u0 + u1 * u1 + u2 * u2);
            }
            float g00 = gls[p * 12 + 0], g01 = gls[p * 12 + 1], g02 = gls[p * 12 + 2];
            float g10 = gls[p * 12 + 3], g11 = gls[p * 12 + 4], g12 = gls[p * 12 + 5];
            float g20 = gls[p * 12 + 6], g21 = gls[p * 12 + 7], g22 = gls[p * 12 + 8];
            float e11 = g11, e22 = g00, e33 = g22;
            float e12 = 0.5f * (g01 + g10);
            float e13 = 0.5f * (g21 + g12);
            float e23 = 0.5f * (g20 + g02);
            float tr = e11 + e22 + e33;
            float en = 0.5f * LAMBDA_L * tr * tr +
                       MU_L * (e11 * e11 + e22 * e22 + e33 * e33 +
                               2.f * (e12 * e12 + e13 * e13 + e23 * e23));
            float exp3 = en * xp3s[p];
            energy_c_out[base + p] = 2.f * exp3;
            float er = wred(exp3);
            ef = wred(ef);
            if (tid == 0) {
                atomicAdd(acc + 0, er);
                atomicAdd(acc + 1, ef);
            }
        }

        if (do_trace) {
            // delta3 seeds into t0..t2 (tangents done)
#pragma unroll
            for (int it = 0; it < 2; ++it) {
                int f = tid + it * NTHREADS;
                int p = f >> 4, blk = f & 15, j0 = blk * 8;
                bf16x8 h3v = *(const bf16x8*)(h3s + swb(p, blk));
                bf16x8 d0, d1, d2;
#pragma unroll
                for (int e = 0; e < 8; ++e) {
                    float h = (float)h3v[e];
                    float fct = 1.f - h * h;
                    d0[e] = (__bf16)(fct * W4ts[j0 + e]);
                    d1[e] = (__bf16)(fct * W4ts[HDIM + j0 + e]);
                    d2[e] = (__bf16)(fct * W4ts[2 * HDIM + j0 + e]);
                }
                int wi = swb(p, blk);
                *(bf16x8*)(t0s + wi) = d0;
                *(bf16x8*)(t1s + wi) = d1;
                *(bf16x8*)(t2s + wi) = d2;
            }
            dnorms64(h1s, h2s, h3s, npart, tid);
            __syncthreads();
            if (tid < PTS) {
                int p = tid;
                nh1s[p] = sum8(npart, 0, p);
                nh2s[p] = sum8(npart, 1, p);
                nh3s[p] = sum8(npart, 2, p);
                float x0 = xss[p * 4], x1 = xss[p * 4 + 1], x2 = xss[p * 4 + 2];
                nxs[p] = x0 * x0 + x1 * x1 + x2 * x2;
            }
            __syncthreads();
            dnorms64(t0s, t1s, t2s, npart, tid);   // ||d3||^2
            __syncthreads();
            float s_acc = 0.f;
            if (tid < PTS) s_acc = sum24(npart, tid) * (1.f + nh2s[tid]);
            {
                __bf16* ib[3] = {t0s, t1s, t2s};
                gemm_bwd<3>(W3, ib, h2s, tid);     // delta2
            }
            __syncthreads();
            dnorms64(t0s, t1s, t2s, npart, tid);   // ||d2||^2
            __syncthreads();
            if (tid < PTS) s_acc += sum24(npart, tid) * (1.f + nh1s[tid]);
            {
                __bf16* ib[3] = {t0s, t1s, t2s};
                gemm_bwd<3>(W2, ib, h1s, tid);     // delta1
            }
            __syncthreads();
            dnorms64(t0s, t1s, t2s, npart, tid);   // ||d1||^2
            __syncthreads();
            if (tid < 64) {
                int p = tid;
                float s = s_acc + sum24(npart, p) * (1.f + nxs[p]) + 3.f * (nh3s[p] + 1.f);
                bool uu = (base + p) < nfixv;
                float su = uu ? s : 0.f;
                float sr = uu ? 0.f : s;
                float cu = uu ? 1.f : 0.f;
                float cr = uu ? 0.f : 1.f;
                su = wred(su); sr = wred(sr); cu = wred(cu); cr = wred(cr);
                if (tid == 0) {
                    atomicAdd(acc + 3, su);
                    atomicAdd(acc + 4, sr);
                    atomicAdd(acc + 5, cu);
                    atomicAdd(acc + 6, cr);
                }
            }
        }
    } else {
        // ================= force path: 64 force points =================
        const int fbase = (bi - nmain) * PTS;
        if (tid < 3 * PTS) xss[(tid / 3) * 4 + (tid % 3)] = fc[fbase * 3 + tid];
        if (tid >= 256 && tid < 512) {
            int e = tid - 256;
            int o = e >> 4, blk = e & 15, j0 = blk * 8;
            bf16x8 pk;
#pragma unroll
            for (int i = 0; i < 8; ++i)
                pk[i] = (__bf16)((o < 3) ? W4[(j0 + i) * 3 + o] : 0.f);
            *(bf16x8*)(W4p + swb(o, blk)) = pk;
        }
        __syncthreads();
#pragma unroll
        for (int it = 0; it < 2; ++it) {
            int f = tid + it * NTHREADS;
            int p = f >> 4, blk = f & 15, j0 = blk * 8;
            float x0 = xss[p * 4], x1 = xss[p * 4 + 1], x2 = xss[p * 4 + 2];
            bf16x8 hv;
#pragma unroll
            for (int jj = 0; jj < 8; ++jj) {
                int j = j0 + jj;
                float z = b1[j] + x0 * W1[j] + x1 * W1[HDIM + j] + x2 * W1[2 * HDIM + j];
                hv[jj] = (__bf16)fast_tanh(z);
            }
            *(bf16x8*)(h1s + swb(p, blk)) = hv;
        }
        {
            __bf16* ib[1] = {h1s};
            gemm_fwd<1>(W2, Wstage, ib, ib, b2, tid);
        }
        {
            __bf16* ib[1] = {h1s};
            gemm_fwd<1>(W3, Wstage, ib, ib, b3, tid);
        }
        __syncthreads();
        if (wid < 4) {
            f32x4 ha = (f32x4){0.f, 0.f, 0.f, 0.f};
#pragma unroll
            for (int ks = 0; ks < 4; ++ks) {
                int kb = ks * 4 + q;
                bf16x8 af = *(const bf16x8*)(W4p + swb(l15, kb));
                bf16x8 bf_ = *(const bf16x8*)(h1s + swb(wid * 16 + l15, kb));
                ha = __builtin_amdgcn_mfma_f32_16x16x32_bf16(af, bf_, ha, 0, 0, 0);
            }
            if (q == 0) {
                int p = wid * 16 + l15;
#pragma unroll
                for (int o = 0; o < 3; ++o) uls[p * 4 + o] = ha[o] + b4[o];
            }
        }
        __syncthreads();
        if (tid < 64) {
            float fsum = uls[tid * 4] * Fv[0] + uls[tid * 4 + 1] * Fv[1] + uls[tid * 4 + 2] * Fv[2];
            fsum = wred(fsum);
            if (tid == 0) atomicAdd(acc + 2, fsum);
        }
    }
}

__global__ void pinn_final(const float* __restrict__ acc, float* __restrict__ out,
                           int Ntot, const int* __restrict__ nfixp) {
    float es = acc[0], ef = acc[1], fl = acc[2];
    float su = acc[3], sr = acc[4], cu = acc[5], cr = acc[6];
    float nfix = (float)nfixp[0];
    float tu = su / fmaxf(cu, 1.f) * nfix;
    float tr = sr / fmaxf(cr, 1.f) * ((float)Ntot - nfix);
    float energy_ans = EMV * (es / (float)Ntot);
    float E_fix = ef * EMV / (float)Ntot;
    float lam = tr / (tu + 1e-12f);
    lam = fminf(fmaxf(lam, 0.001f), 1000.f);
    out[0] = energy_ans - fl + lam * E_fix;
}

extern "C" void kernel_launch(void* const* d_in, const int* in_sizes, int n_in,
                              void* d_out, int out_size, void* d_ws, size_t ws_size,
                              hipStream_t stream) {
    const float* xPhys = (const float*)d_in[0];
    const float* coord = (const float*)d_in[1];
    const float* W1 = (const float*)d_in[2];
    const float* b1 = (const float*)d_in[3];
    const float* W2 = (const float*)d_in[4];
    const float* b2 = (const float*)d_in[5];
    const float* W3 = (const float*)d_in[6];
    const float* b3 = (const float*)d_in[7];
    const float* W4 = (const float*)d_in[8];
    const float* b4 = (const float*)d_in[9];
    const float* fc = (const float*)d_in[10];
    const float* Fv = (const float*)d_in[11];
    const int* nfix = (const int*)d_in[12];

    const int N = in_sizes[0];        // 65536
    const int NF = in_sizes[10] / 3;  // 4096
    float* out = (float*)d_out;
    float* acc = (float*)d_ws;  // [energy, efix, force, su, sr, cnt_u, cnt_r]

    const int nmain = N / PTS;        // 1024
    const int nforce = NF / PTS;      // 64
    hipMemsetAsync(acc, 0, 8 * sizeof(float), stream);
    pinn_all<<<dim3(nmain + nforce), dim3(NTHREADS), 0, stream>>>(
        xPhys, coord, W1, b1, W2, b2, W3, b3, W4, b4, fc, Fv, nfix,
        out + 1, out + 1 + N, acc, nmain);
    pinn_final<<<dim3(1), dim3(1), 0, stream>>>(acc, out, N, nfix);
}